// Round 9
// baseline (1121.114 us; speedup 1.0000x reference)
//
#include <hip/hip_runtime.h>

#define NDIM 128
#define NB 512                 // number of dst bins == 2 * 256 CUs (perfect 2 rounds)
#define BINSZ_MAX 256          // max nodes per bin (=> N <= 131072)
#define CAP_SHIFT 12
#define BIN_CAP 4096           // padded per-bin edge capacity (avg fill ~3136, 17 sigma)
#define TILE 4096              // edges per bin_scatter block

typedef __attribute__((ext_vector_type(8))) short short8;
typedef __attribute__((ext_vector_type(4))) float f32x4;

__device__ inline unsigned short f2bf_rne(float f) {
    unsigned int u = __float_as_uint(f);
    unsigned int r = u + 0x7fffu + ((u >> 16) & 1u);
    return (unsigned short)(r >> 16);
}
__device__ inline float bf2f(unsigned short s) {
    return __uint_as_float(((unsigned int)s) << 16);
}
__device__ inline float bf_lo(unsigned int u) { return __uint_as_float(u << 16); }
__device__ inline float bf_hi(unsigned int u) { return __uint_as_float(u & 0xffff0000u); }

// ---------------------------------------------------------------------------
// Kernel 1: h = x @ W, pure bf16 MFMA (storage rounding dominates anyway).
// W staged in LDS transposed bf16 (32 KB) with XOR k-swizzle.
// Block = 256 thr = 4 waves; 16 rows/wave -> 64 rows/block. Grid-stride.
// mfma_f32_16x16x32_bf16: A[row=lane&15][k=(lane>>4)*8+j],
//                         B[k][col=lane&15], C[col=lane&15][row=(lane>>4)*4+r]
// ---------------------------------------------------------------------------
__global__ __launch_bounds__(256) void gemm128_bf16(const float* __restrict__ x,
                                                    const float* __restrict__ W,
                                                    unsigned short* __restrict__ h,
                                                    int n_nodes, int ntiles) {
    __shared__ __align__(16) unsigned short Wt[NDIM * NDIM];  // 32 KB
    const int tid = threadIdx.x;

    const float4* W4 = (const float4*)W;
#pragma unroll
    for (int i = 0; i < 16; ++i) {
        const int vid = i * 256 + tid;
        const int k = vid >> 5;
        const int c4 = (vid & 31) * 4;
        const float4 w = W4[vid];
        const float* wf = (const float*)&w;
#pragma unroll
        for (int j = 0; j < 4; ++j) {
            const int col = c4 + j;
            const int ksw = k ^ ((col & 7) << 3);
            Wt[col * NDIM + ksw] = f2bf_rne(wf[j]);
        }
    }
    __syncthreads();

    const int wave = tid >> 6;
    const int lane = tid & 63;
    const int lc = lane & 15;
    const int kq = (lane >> 4) * 8;

    for (int tile = blockIdx.x; tile < ntiles; tile += gridDim.x) {
        const int row0 = tile * 64 + wave * 16;

        int arow = row0 + lc;
        arow = (arow < n_nodes) ? arow : (n_nodes - 1);
        const float* xr = x + (size_t)arow * NDIM;

        f32x4 acc[8];
#pragma unroll
        for (int t = 0; t < 8; ++t) acc[t] = (f32x4){0.f, 0.f, 0.f, 0.f};

#pragma unroll
        for (int ks = 0; ks < 4; ++ks) {
            const int kbase = ks * 32 + kq;
            const float4 v0 = *(const float4*)(xr + kbase);
            const float4 v1 = *(const float4*)(xr + kbase + 4);
            const float* vf0 = (const float*)&v0;
            const float* vf1 = (const float*)&v1;

            short8 ah;
#pragma unroll
            for (int j = 0; j < 4; ++j) {
                ah[j]     = (short)f2bf_rne(vf0[j]);
                ah[j + 4] = (short)f2bf_rne(vf1[j]);
            }

#pragma unroll
            for (int t = 0; t < 8; ++t) {
                const int col = t * 16 + lc;
                const int ksw = kbase ^ ((col & 7) << 3);
                const short8 bh = *(const short8*)&Wt[col * NDIM + ksw];
                acc[t] = __builtin_amdgcn_mfma_f32_16x16x32_bf16(ah, bh, acc[t], 0, 0, 0);
            }
        }

        const int orow0 = row0 + (lane >> 4) * 4;
#pragma unroll
        for (int t = 0; t < 8; ++t) {
#pragma unroll
            for (int r = 0; r < 4; ++r) {
                const int row = orow0 + r;
                if (row < n_nodes) {
                    h[(size_t)row * NDIM + t * 16 + lc] = f2bf_rne(acc[t][r]);
                }
            }
        }
    }
}

// ---------------------------------------------------------------------------
// init_cursor: binCursor[i] = i * BIN_CAP
// ---------------------------------------------------------------------------
__global__ __launch_bounds__(256) void init_cursor(int* __restrict__ binCursor, int nb) {
    const int i = blockIdx.x * 256 + threadIdx.x;
    if (i < nb) binCursor[i] = i << CAP_SHIFT;
}

// ---------------------------------------------------------------------------
// bin_scatter: tile of TILE edges; LDS-sort by bin (bin = dst/BINSZ via
// host-computed magic multiply); reserve contiguous per-(block,bin) runs in
// the bin's padded region; write packed (dstLow<<24|src) u32s.
// ---------------------------------------------------------------------------
__global__ __launch_bounds__(256) void bin_scatter(const int* __restrict__ src,
                                                   const int* __restrict__ dst,
                                                   int* __restrict__ binCursor,
                                                   unsigned int* __restrict__ binned,
                                                   int n_edges,
                                                   unsigned int magic, int shift, int binsz) {
    __shared__ int lhist[NB];
    __shared__ int lstart[NB];
    __shared__ int lcur[NB];     // cursors, then reused as global bases
    __shared__ int lsums[256];
    __shared__ unsigned int lsorted[TILE];
    __shared__ unsigned short lbin[TILE];
    const int tid = threadIdx.x;
    const int base = blockIdx.x * TILE;
    const int count = min(TILE, n_edges - base);

    for (int i = tid; i < NB; i += 256) lhist[i] = 0;
    __syncthreads();

    int mybin[16];
    unsigned int mypacked[16];
#pragma unroll
    for (int j = 0; j < 16; ++j) {
        const int idx = tid + j * 256;  // coalesced
        if (idx < count) {
            const int d = __builtin_nontemporal_load(dst + base + idx);
            const int s = __builtin_nontemporal_load(src + base + idx);
            const int bn = (int)(((unsigned long long)(unsigned int)d * magic) >> shift);
            const int dl = d - bn * binsz;
            mybin[j] = bn;
            mypacked[j] = ((unsigned int)dl << 24) | (unsigned int)s;
            atomicAdd(&lhist[bn], 1);
        } else {
            mybin[j] = -1;
            mypacked[j] = 0;
        }
    }
    __syncthreads();

    // exclusive scan over NB=512 bins (2 elems/thread)
    const int a = lhist[2 * tid], b = lhist[2 * tid + 1];
    lsums[tid] = a + b;
    __syncthreads();
    for (int off = 1; off < 256; off <<= 1) {
        const int tmp = (tid >= off) ? lsums[tid - off] : 0;
        __syncthreads();
        lsums[tid] += tmp;
        __syncthreads();
    }
    const int ex = (tid > 0) ? lsums[tid - 1] : 0;
    lstart[2 * tid] = ex;
    lstart[2 * tid + 1] = ex + a;
    lcur[2 * tid] = ex;
    lcur[2 * tid + 1] = ex + a;
    __syncthreads();

    // LDS scatter into bin-sorted order + bin LUT
#pragma unroll
    for (int j = 0; j < 16; ++j) {
        if (mybin[j] >= 0) {
            const int pos = atomicAdd(&lcur[mybin[j]], 1);
            lsorted[pos] = mypacked[j];
            lbin[pos] = (unsigned short)mybin[j];
        }
    }
    __syncthreads();

    // reserve global runs per bin (lcur becomes global base per bin)
    for (int i = tid; i < NB; i += 256) {
        const int c = lhist[i];
        lcur[i] = c ? atomicAdd(&binCursor[i], c) : 0;
    }
    __syncthreads();

    // sequential write-out; per-slot bin via LUT
    for (int p = tid; p < count; p += 256) {
        const int bn = lbin[p];
        const int addr = lcur[bn] + (p - lstart[bn]);
        if ((addr >> CAP_SHIFT) == bn) {  // overflow guard
            binned[addr] = lsorted[p];
        }
    }
}

// ---------------------------------------------------------------------------
// gather_bins: one block per bin; [BINSZ][128] f32 accumulator in LDS (128 KB
// max). Waves stream the bin's packed edges; per edge each lane reads 1 uint
// (2 bf16 dims) of h[src] (coalesced 256B/row) and ds_add_f32 into the
// accumulator row dstLow. Epilogue fuses out = x + relu(acc + b).
// 512 bins at 1 block/CU = two perfectly balanced rounds.
// ---------------------------------------------------------------------------
__global__ __launch_bounds__(512) void gather_bins(const unsigned short* __restrict__ h,
                                                   const unsigned int* __restrict__ binned,
                                                   const int* __restrict__ binCursor,
                                                   const float* __restrict__ x,
                                                   const float* __restrict__ bias,
                                                   float* __restrict__ out,
                                                   int n_nodes, int binsz) {
    __shared__ float acc[BINSZ_MAX * NDIM];  // 128 KB
    const int b = blockIdx.x;
    const int node0 = b * binsz;
    if (node0 >= n_nodes) return;
    const int nodesInBin = min(binsz, n_nodes - node0);

    const int tid = threadIdx.x;
    const int wave = tid >> 6;
    const int lane = tid & 63;
    const int c = lane * 2;  // dims c, c+1

    // zero the live part of the accumulator
    const int nf4 = binsz * (NDIM / 4);
    for (int i = tid; i < nf4; i += 512) {
        ((float4*)acc)[i] = make_float4(0.f, 0.f, 0.f, 0.f);
    }
    __syncthreads();

    const int gbase = b << CAP_SHIFT;
    int count = binCursor[b] - gbase;
    count = min(count, BIN_CAP);

    // per-wave chunk, rounded to multiple of 8 for aligned uint4 pair loads
    const int per = ((count + 63) >> 6) << 3;
    const int es0 = wave * per;
    const int es1 = min(es0 + per, count);

    int i = es0;
    for (; i + 8 <= es1; i += 8) {
        const uint4 pa = *(const uint4*)(binned + gbase + i);
        const uint4 pb = *(const uint4*)(binned + gbase + i + 4);
        unsigned int p[8] = {pa.x, pa.y, pa.z, pa.w, pb.x, pb.y, pb.z, pb.w};
        unsigned int v[8];
#pragma unroll
        for (int k = 0; k < 8; ++k) {
            const int s = (int)(p[k] & 0xFFFFFFu);
            v[k] = *(const unsigned int*)(h + (size_t)s * NDIM + c);
        }
#pragma unroll
        for (int k = 0; k < 8; ++k) {
            float* ap = acc + (p[k] >> 24) * NDIM + c;
            atomicAdd(ap, bf_lo(v[k]));
            atomicAdd(ap + 1, bf_hi(v[k]));
        }
    }
    for (; i < es1; ++i) {
        const unsigned int p0 = binned[gbase + i];
        const int s = (int)(p0 & 0xFFFFFFu);
        const unsigned int v0 = *(const unsigned int*)(h + (size_t)s * NDIM + c);
        float* ap = acc + (p0 >> 24) * NDIM + c;
        atomicAdd(ap, bf_lo(v0));
        atomicAdd(ap + 1, bf_hi(v0));
    }
    __syncthreads();

    // epilogue: out[node] = x[node] + relu(acc + b), coalesced float4
    for (int t = tid; t < nf4; t += 512) {
        const int nrow = t >> 5;  // 32 float4 per row
        if (nrow >= nodesInBin) break;
        const int node = node0 + nrow;
        const int dq = (t & 31) * 4;
        const f32x4 av = ((const f32x4*)acc)[t];
        const f32x4 xv = __builtin_nontemporal_load((const f32x4*)(x + (size_t)node * NDIM + dq));
        const f32x4 bv = *(const f32x4*)(bias + dq);
        f32x4 r;
        r.x = xv.x + fmaxf(av.x + bv.x, 0.f);
        r.y = xv.y + fmaxf(av.y + bv.y, 0.f);
        r.z = xv.z + fmaxf(av.z + bv.z, 0.f);
        r.w = xv.w + fmaxf(av.w + bv.w, 0.f);
        __builtin_nontemporal_store(r, (f32x4*)(out + (size_t)node * NDIM + dq));
    }
}

// ---------------------------------------------------------------------------
// Fallback (only if ws too small / N too big): atomic scatter + finalize.
// ---------------------------------------------------------------------------
__global__ __launch_bounds__(256) void scatter_add_bf(const unsigned short* __restrict__ h,
                                                      const int* __restrict__ src,
                                                      const int* __restrict__ dst,
                                                      float* __restrict__ agg,
                                                      int n_edges) {
    const int gid = blockIdx.x * 256 + threadIdx.x;
    const int e = gid >> 6;
    if (e >= n_edges) return;
    const int c = (gid & 63) * 2;
    const int s = src[e];
    const int d = dst[e];
    const unsigned int v = *(const unsigned int*)(h + (size_t)s * NDIM + c);
    float* ap = agg + (size_t)d * NDIM + c;
    atomicAdd(ap + 0, bf_lo(v));
    atomicAdd(ap + 1, bf_hi(v));
}

__global__ __launch_bounds__(256) void finalize(const float* __restrict__ x,
                                                const float* __restrict__ b,
                                                float* __restrict__ out,
                                                int n_vec4) {
    const int i = blockIdx.x * 256 + threadIdx.x;
    if (i >= n_vec4) return;
    float4 xv = ((const float4*)x)[i];
    float4 av = ((float4*)out)[i];
    const int dcol = (i * 4) & (NDIM - 1);
    float4 bv = *(const float4*)(b + dcol);
    float4 r;
    r.x = xv.x + fmaxf(av.x + bv.x, 0.f);
    r.y = xv.y + fmaxf(av.y + bv.y, 0.f);
    r.z = xv.z + fmaxf(av.z + bv.z, 0.f);
    r.w = xv.w + fmaxf(av.w + bv.w, 0.f);
    ((float4*)out)[i] = r;
}

extern "C" void kernel_launch(void* const* d_in, const int* in_sizes, int n_in,
                              void* d_out, int out_size, void* d_ws, size_t ws_size,
                              hipStream_t stream) {
    const float* x    = (const float*)d_in[0];
    const int*   esrc = (const int*)d_in[1];
    const int*   edst = (const int*)d_in[2];
    const float* W    = (const float*)d_in[3];
    const float* b    = (const float*)d_in[4];
    float* out = (float*)d_out;

    const int n_nodes = in_sizes[0] / NDIM;
    const int n_edges = in_sizes[1];
    const int ntiles = (n_nodes + 63) / 64;

    // bin size + host-computed magic divide (exact for all d < n_nodes)
    const int binsz = (n_nodes + NB - 1) / NB;
    unsigned int magic = 0;
    int shift = 0;
    for (int s = 16; s <= 31; ++s) {
        const unsigned long long m = ((1ULL << s) + binsz - 1) / (unsigned long long)binsz;
        const unsigned long long e = m * (unsigned long long)binsz - (1ULL << s);
        const unsigned long long dmax = (n_nodes > 1) ? (unsigned long long)(n_nodes - 1) : 1ULL;
        if (m <= 0xFFFFFFFFULL && e * dmax < (1ULL << s)) {
            magic = (unsigned int)m;
            shift = s;
            break;
        }
    }

    // Workspace layout
    unsigned short* h = (unsigned short*)d_ws;                 // N*128 bf16
    int* binCursor = (int*)(h + (size_t)n_nodes * NDIM);       // NB
    unsigned int* binned = (unsigned int*)(binCursor + NB);    // NB*BIN_CAP

    const size_t required = (size_t)n_nodes * NDIM * 2 +
                            (size_t)NB * 4 +
                            ((size_t)NB << CAP_SHIFT) * 4;

    // h = x @ W (pure bf16 MFMA)
    const int gblocks = (ntiles < 2048) ? ntiles : 2048;
    gemm128_bf16<<<gblocks, 256, 0, stream>>>(x, W, h, n_nodes, ntiles);

    if (binsz <= BINSZ_MAX && magic != 0 && ws_size >= required) {
        init_cursor<<<(NB + 255) / 256, 256, 0, stream>>>(binCursor, NB);
        const int ntile_e = (n_edges + TILE - 1) / TILE;
        bin_scatter<<<ntile_e, 256, 0, stream>>>(esrc, edst, binCursor, binned,
                                                 n_edges, magic, shift, binsz);
        gather_bins<<<NB, 512, 0, stream>>>(h, binned, binCursor, x, b, out,
                                            n_nodes, binsz);
    } else {
        // fallback: atomic scatter
        hipMemsetAsync(d_out, 0, (size_t)out_size * sizeof(float), stream);
        const long long st = (long long)n_edges * 64;
        scatter_add_bf<<<(int)((st + 255) / 256), 256, 0, stream>>>(h, esrc, edst, out, n_edges);
        const int n_vec4 = n_nodes * NDIM / 4;
        finalize<<<(n_vec4 + 255) / 256, 256, 0, stream>>>(x, b, out, n_vec4);
    }
}

// Round 10
// 148.783 us; speedup vs baseline: 7.5352x; 7.5352x over previous
//
#include <hip/hip_runtime.h>

#define NDIM 128
#define BIN_SHIFT 8
#define BIN_NODES 256          // 1 << BIN_SHIFT
#define MAX_BINS 512           // supports up to 131072 nodes
#define TILE 4096              // edges per bin_scatter block
#define CAP_SHIFT 13
#define BIN_CAP 8192           // padded per-bin capacity (avg fill ~4092)
#define CSR_CAP 6144           // per-bin LDS staging in csr_fill

typedef __attribute__((ext_vector_type(8))) short short8;
typedef __attribute__((ext_vector_type(4))) float f32x4;

__device__ inline unsigned short f2bf_rne(float f) {
    unsigned int u = __float_as_uint(f);
    unsigned int r = u + 0x7fffu + ((u >> 16) & 1u);
    return (unsigned short)(r >> 16);
}
__device__ inline float bf2f(unsigned short s) {
    return __uint_as_float(((unsigned int)s) << 16);
}
__device__ inline float bf_lo(unsigned int u) { return __uint_as_float(u << 16); }
__device__ inline float bf_hi(unsigned int u) { return __uint_as_float(u & 0xffff0000u); }

// ---------------------------------------------------------------------------
// Kernel 1: h = x @ W, pure bf16 MFMA (validated R9: absmax unchanged vs
// split-precision — h's bf16 storage rounding dominates).
// W staged in LDS transposed bf16 (32 KB) with XOR k-swizzle.
// Block = 256 thr = 4 waves; 16 rows/wave -> 64 rows/block. Grid-stride.
// mfma_f32_16x16x32_bf16: A[row=lane&15][k=(lane>>4)*8+j],
//                         B[k][col=lane&15], C[col=lane&15][row=(lane>>4)*4+r]
// ---------------------------------------------------------------------------
__global__ __launch_bounds__(256) void gemm128_bf16(const float* __restrict__ x,
                                                    const float* __restrict__ W,
                                                    unsigned short* __restrict__ h,
                                                    int n_nodes, int ntiles) {
    __shared__ __align__(16) unsigned short Wt[NDIM * NDIM];  // 32 KB
    const int tid = threadIdx.x;

    const float4* W4 = (const float4*)W;
#pragma unroll
    for (int i = 0; i < 16; ++i) {
        const int vid = i * 256 + tid;
        const int k = vid >> 5;
        const int c4 = (vid & 31) * 4;
        const float4 w = W4[vid];
        const float* wf = (const float*)&w;
#pragma unroll
        for (int j = 0; j < 4; ++j) {
            const int col = c4 + j;
            const int ksw = k ^ ((col & 7) << 3);
            Wt[col * NDIM + ksw] = f2bf_rne(wf[j]);
        }
    }
    __syncthreads();

    const int wave = tid >> 6;
    const int lane = tid & 63;
    const int lc = lane & 15;
    const int kq = (lane >> 4) * 8;

    for (int tile = blockIdx.x; tile < ntiles; tile += gridDim.x) {
        const int row0 = tile * 64 + wave * 16;

        int arow = row0 + lc;
        arow = (arow < n_nodes) ? arow : (n_nodes - 1);
        const float* xr = x + (size_t)arow * NDIM;

        f32x4 acc[8];
#pragma unroll
        for (int t = 0; t < 8; ++t) acc[t] = (f32x4){0.f, 0.f, 0.f, 0.f};

#pragma unroll
        for (int ks = 0; ks < 4; ++ks) {
            const int kbase = ks * 32 + kq;
            const float4 v0 = *(const float4*)(xr + kbase);
            const float4 v1 = *(const float4*)(xr + kbase + 4);
            const float* vf0 = (const float*)&v0;
            const float* vf1 = (const float*)&v1;

            short8 ah;
#pragma unroll
            for (int j = 0; j < 4; ++j) {
                ah[j]     = (short)f2bf_rne(vf0[j]);
                ah[j + 4] = (short)f2bf_rne(vf1[j]);
            }

#pragma unroll
            for (int t = 0; t < 8; ++t) {
                const int col = t * 16 + lc;
                const int ksw = kbase ^ ((col & 7) << 3);
                const short8 bh = *(const short8*)&Wt[col * NDIM + ksw];
                acc[t] = __builtin_amdgcn_mfma_f32_16x16x32_bf16(ah, bh, acc[t], 0, 0, 0);
            }
        }

        const int orow0 = row0 + (lane >> 4) * 4;
#pragma unroll
        for (int t = 0; t < 8; ++t) {
#pragma unroll
            for (int r = 0; r < 4; ++r) {
                const int row = orow0 + r;
                if (row < n_nodes) {
                    h[(size_t)row * NDIM + t * 16 + lc] = f2bf_rne(acc[t][r]);
                }
            }
        }
    }
}

// ---------------------------------------------------------------------------
// init_cursor: binCursor[i] = i * BIN_CAP
// ---------------------------------------------------------------------------
__global__ __launch_bounds__(256) void init_cursor(int* __restrict__ binCursor, int nb) {
    const int i = blockIdx.x * 256 + threadIdx.x;
    if (i < nb) binCursor[i] = i << CAP_SHIFT;
}

// ---------------------------------------------------------------------------
// bin_scatter: tile of TILE edges; LDS-sort by 256-node bin; reserve
// contiguous per-(block,bin) runs in the bin's padded region; write packed
// (dstLow<<24|src) u32s. Bin of each sorted slot kept in a ushort LUT.
// ---------------------------------------------------------------------------
__global__ __launch_bounds__(256) void bin_scatter(const int* __restrict__ src,
                                                   const int* __restrict__ dst,
                                                   int* __restrict__ binCursor,
                                                   unsigned int* __restrict__ binned,
                                                   int n_edges, int nb) {
    __shared__ int lhist[MAX_BINS];
    __shared__ int lstart[MAX_BINS];
    __shared__ int lcur[MAX_BINS];     // cursors, then reused as global bases
    __shared__ int lsums[256];
    __shared__ unsigned int lsorted[TILE];
    __shared__ unsigned short lbin[TILE];
    const int tid = threadIdx.x;
    const int base = blockIdx.x * TILE;
    const int count = min(TILE, n_edges - base);

    for (int i = tid; i < MAX_BINS; i += 256) lhist[i] = 0;
    __syncthreads();

    int mybin[16];
    unsigned int mypacked[16];
#pragma unroll
    for (int j = 0; j < 16; ++j) {
        const int idx = tid + j * 256;  // coalesced
        if (idx < count) {
            const int d = __builtin_nontemporal_load(dst + base + idx);
            const int s = __builtin_nontemporal_load(src + base + idx);
            mybin[j] = d >> BIN_SHIFT;
            mypacked[j] = ((unsigned int)(d & (BIN_NODES - 1)) << 24) | (unsigned int)s;
            atomicAdd(&lhist[mybin[j]], 1);
        } else {
            mybin[j] = -1;
            mypacked[j] = 0;
        }
    }
    __syncthreads();

    // exclusive scan over MAX_BINS (2 elems/thread)
    const int a = lhist[2 * tid], b = lhist[2 * tid + 1];
    lsums[tid] = a + b;
    __syncthreads();
    for (int off = 1; off < 256; off <<= 1) {
        const int tmp = (tid >= off) ? lsums[tid - off] : 0;
        __syncthreads();
        lsums[tid] += tmp;
        __syncthreads();
    }
    const int ex = (tid > 0) ? lsums[tid - 1] : 0;
    lstart[2 * tid] = ex;
    lstart[2 * tid + 1] = ex + a;
    lcur[2 * tid] = ex;
    lcur[2 * tid + 1] = ex + a;
    __syncthreads();

    // LDS scatter into bin-sorted order + bin LUT
#pragma unroll
    for (int j = 0; j < 16; ++j) {
        if (mybin[j] >= 0) {
            const int pos = atomicAdd(&lcur[mybin[j]], 1);
            lsorted[pos] = mypacked[j];
            lbin[pos] = (unsigned short)mybin[j];
        }
    }
    __syncthreads();

    // reserve global runs per bin (lcur becomes global base per bin)
    for (int i = tid; i < nb; i += 256) {
        const int c = lhist[i];
        lcur[i] = c ? atomicAdd(&binCursor[i], c) : 0;
    }
    __syncthreads();

    // sequential write-out; per-slot bin via LUT (no binary search)
    for (int p = tid; p < count; p += 256) {
        const int bn = lbin[p];
        const int addr = lcur[bn] + (p - lstart[bn]);
        if ((addr >> CAP_SHIFT) == bn) {  // overflow guard
            binned[addr] = lsorted[p];
        }
    }
}

// ---------------------------------------------------------------------------
// csr_fill: one block per bin -> deg[], offs[], srcsorted[] (padded layout).
// ---------------------------------------------------------------------------
__global__ __launch_bounds__(256) void csr_fill(const unsigned int* __restrict__ binned,
                                                const int* __restrict__ binCursor,
                                                int* __restrict__ deg,
                                                int* __restrict__ offs,
                                                int* __restrict__ srcsorted,
                                                int n_nodes) {
    __shared__ int lhist[BIN_NODES];
    __shared__ int lscan[BIN_NODES];
    __shared__ int lcur[BIN_NODES];
    __shared__ unsigned int lin[CSR_CAP];
    __shared__ int lout[CSR_CAP];
    const int b = blockIdx.x;
    const int tid = threadIdx.x;
    const int gbase = b << CAP_SHIFT;
    int count = binCursor[b] - gbase;
    count = min(count, BIN_CAP);
    const int node0 = b * BIN_NODES;

    lhist[tid] = 0;
    __syncthreads();

    const bool fits = (count <= CSR_CAP);

    if (fits) {
        for (int p = tid; p < count; p += 256) {
            const unsigned int v = binned[gbase + p];
            lin[p] = v;
            atomicAdd(&lhist[v >> 24], 1);
        }
    } else {
        for (int p = tid; p < count; p += 256) {
            atomicAdd(&lhist[binned[gbase + p] >> 24], 1);
        }
    }
    __syncthreads();

    const int myv = lhist[tid];
    lscan[tid] = myv;
    __syncthreads();
    for (int off = 1; off < 256; off <<= 1) {
        const int tmp = (tid >= off) ? lscan[tid - off] : 0;
        __syncthreads();
        lscan[tid] += tmp;
        __syncthreads();
    }
    const int ex = lscan[tid] - myv;

    const int node = node0 + tid;
    if (node < n_nodes) {
        deg[node] = myv;
        offs[node] = gbase + ex;
    }
    lcur[tid] = ex;
    __syncthreads();

    if (fits) {
        for (int p = tid; p < count; p += 256) {
            const unsigned int v = lin[p];
            const int pos = atomicAdd(&lcur[v >> 24], 1);
            lout[pos] = (int)(v & 0xFFFFFFu);
        }
        __syncthreads();
        for (int p = tid; p < count; p += 256) {
            srcsorted[gbase + p] = lout[p];
        }
    } else {
        for (int p = tid; p < count; p += 256) {
            const unsigned int v = binned[gbase + p];
            const int pos = atomicAdd(&lcur[v >> 24], 1);
            srcsorted[gbase + pos] = (int)(v & 0xFFFFFFu);
        }
    }
}

// ---------------------------------------------------------------------------
// gather_nodes: one wave per node; lane owns 2 cols (1 uint of h).
// 8-deep edge unroll for MLP. out[n] = x[n] + relu(sum h[src] + b)
// ---------------------------------------------------------------------------
__global__ __launch_bounds__(256) void gather_nodes(const unsigned short* __restrict__ h,
                                                    const int* __restrict__ srcsorted,
                                                    const int* __restrict__ offs,
                                                    const int* __restrict__ deg,
                                                    const float* __restrict__ x,
                                                    const float* __restrict__ bias,
                                                    float* __restrict__ out,
                                                    int n_nodes) {
    const int gid = blockIdx.x * 256 + threadIdx.x;
    const int node = gid >> 6;
    if (node >= n_nodes) return;
    const int lane = threadIdx.x & 63;
    const int c = lane * 2;

    const int start = offs[node];
    const int cnt = deg[node];

    float ax = 0.f, ay = 0.f;
    int j = 0;
    for (; j + 8 <= cnt; j += 8) {
        int s[8];
#pragma unroll
        for (int k = 0; k < 8; ++k) s[k] = __builtin_nontemporal_load(srcsorted + start + j + k);
        unsigned int v[8];
#pragma unroll
        for (int k = 0; k < 8; ++k) v[k] = *(const unsigned int*)(h + (size_t)s[k] * NDIM + c);
#pragma unroll
        for (int k = 0; k < 8; ++k) { ax += bf_lo(v[k]); ay += bf_hi(v[k]); }
    }
    for (; j + 4 <= cnt; j += 4) {
        int s[4];
#pragma unroll
        for (int k = 0; k < 4; ++k) s[k] = __builtin_nontemporal_load(srcsorted + start + j + k);
        unsigned int v[4];
#pragma unroll
        for (int k = 0; k < 4; ++k) v[k] = *(const unsigned int*)(h + (size_t)s[k] * NDIM + c);
#pragma unroll
        for (int k = 0; k < 4; ++k) { ax += bf_lo(v[k]); ay += bf_hi(v[k]); }
    }
    for (; j < cnt; ++j) {
        const int s0 = __builtin_nontemporal_load(srcsorted + start + j);
        const unsigned int v0 = *(const unsigned int*)(h + (size_t)s0 * NDIM + c);
        ax += bf_lo(v0);
        ay += bf_hi(v0);
    }

    const float2 xv = *(const float2*)(x + (size_t)node * NDIM + c);
    const float2 bv = *(const float2*)(bias + c);
    float2 r;
    r.x = xv.x + fmaxf(ax + bv.x, 0.f);
    r.y = xv.y + fmaxf(ay + bv.y, 0.f);
    *(float2*)(out + (size_t)node * NDIM + c) = r;
}

// ---------------------------------------------------------------------------
// Fallback (only if ws too small): atomic scatter from row-major bf16 h.
// ---------------------------------------------------------------------------
__global__ __launch_bounds__(256) void scatter_add_bf(const unsigned short* __restrict__ h,
                                                      const int* __restrict__ src,
                                                      const int* __restrict__ dst,
                                                      float* __restrict__ agg,
                                                      int n_edges) {
    const int gid = blockIdx.x * 256 + threadIdx.x;
    const int e = gid >> 6;
    if (e >= n_edges) return;
    const int c = (gid & 63) * 2;
    const int s = src[e];
    const int d = dst[e];
    const unsigned int v = *(const unsigned int*)(h + (size_t)s * NDIM + c);
    float* ap = agg + (size_t)d * NDIM + c;
    atomicAdd(ap + 0, bf_lo(v));
    atomicAdd(ap + 1, bf_hi(v));
}

__global__ __launch_bounds__(256) void finalize(const float* __restrict__ x,
                                                const float* __restrict__ b,
                                                float* __restrict__ out,
                                                int n_vec4) {
    const int i = blockIdx.x * 256 + threadIdx.x;
    if (i >= n_vec4) return;
    float4 xv = ((const float4*)x)[i];
    float4 av = ((float4*)out)[i];
    const int dcol = (i * 4) & (NDIM - 1);
    float4 bv = *(const float4*)(b + dcol);
    float4 r;
    r.x = xv.x + fmaxf(av.x + bv.x, 0.f);
    r.y = xv.y + fmaxf(av.y + bv.y, 0.f);
    r.z = xv.z + fmaxf(av.z + bv.z, 0.f);
    r.w = xv.w + fmaxf(av.w + bv.w, 0.f);
    ((float4*)out)[i] = r;
}

extern "C" void kernel_launch(void* const* d_in, const int* in_sizes, int n_in,
                              void* d_out, int out_size, void* d_ws, size_t ws_size,
                              hipStream_t stream) {
    const float* x    = (const float*)d_in[0];
    const int*   esrc = (const int*)d_in[1];
    const int*   edst = (const int*)d_in[2];
    const float* W    = (const float*)d_in[3];
    const float* b    = (const float*)d_in[4];
    float* out = (float*)d_out;

    const int n_nodes = in_sizes[0] / NDIM;
    const int n_edges = in_sizes[1];
    const int nb = (n_nodes + BIN_NODES - 1) / BIN_NODES;
    const int ntiles = (n_nodes + 63) / 64;

    // Workspace layout
    unsigned short* h = (unsigned short*)d_ws;                 // N*128 bf16
    int* deg       = (int*)(h + (size_t)n_nodes * NDIM);       // N
    int* offs      = deg + n_nodes;                            // N
    int* binCursor = offs + n_nodes;                           // MAX_BINS
    unsigned int* binned = (unsigned int*)(binCursor + MAX_BINS);  // nb*BIN_CAP
    int* srcsorted = (int*)(binned + ((size_t)nb << CAP_SHIFT));   // nb*BIN_CAP

    const size_t required = (size_t)n_nodes * NDIM * 2 +
                            (size_t)(2 * n_nodes + MAX_BINS) * 4 +
                            ((size_t)nb << CAP_SHIFT) * 8;

    // h = x @ W (pure bf16 MFMA), grid-stride
    const int gblocks = (ntiles < 2048) ? ntiles : 2048;
    gemm128_bf16<<<gblocks, 256, 0, stream>>>(x, W, h, n_nodes, ntiles);

    if (nb <= MAX_BINS && ws_size >= required) {
        init_cursor<<<(nb + 255) / 256, 256, 0, stream>>>(binCursor, nb);
        const int ntile_e = (n_edges + TILE - 1) / TILE;
        bin_scatter<<<ntile_e, 256, 0, stream>>>(esrc, edst, binCursor, binned, n_edges, nb);
        csr_fill<<<nb, 256, 0, stream>>>(binned, binCursor, deg, offs, srcsorted, n_nodes);

        const long long gthreads = (long long)n_nodes * 64;
        gather_nodes<<<(int)((gthreads + 255) / 256), 256, 0, stream>>>(
            h, srcsorted, offs, deg, x, b, out, n_nodes);
    } else {
        // fallback: atomic scatter
        hipMemsetAsync(d_out, 0, (size_t)out_size * sizeof(float), stream);
        const long long st = (long long)n_edges * 64;
        scatter_add_bf<<<(int)((st + 255) / 256), 256, 0, stream>>>(h, esrc, edst, out, n_edges);
        const int n_vec4 = n_nodes * NDIM / 4;
        finalize<<<(n_vec4 + 255) / 256, 256, 0, stream>>>(x, b, out, n_vec4);
    }
}

// Round 11
// 140.892 us; speedup vs baseline: 7.9573x; 1.0560x over previous
//
#include <hip/hip_runtime.h>

#define NDIM 128
#define BIN_SHIFT 8
#define BIN_NODES 256          // 1 << BIN_SHIFT
#define MAX_BINS 512           // supports up to 131072 nodes
#define TILE 4096              // edges per bin-role block
#define CAP_SHIFT 13
#define BIN_CAP 8192           // padded per-bin capacity (avg fill ~4092)
#define CSR_CAP 6144           // per-bin LDS staging in csr_fill

typedef __attribute__((ext_vector_type(8))) short short8;
typedef __attribute__((ext_vector_type(4))) float f32x4;

__device__ inline unsigned short f2bf_rne(float f) {
    unsigned int u = __float_as_uint(f);
    unsigned int r = u + 0x7fffu + ((u >> 16) & 1u);
    return (unsigned short)(r >> 16);
}
__device__ inline float bf2f(unsigned short s) {
    return __uint_as_float(((unsigned int)s) << 16);
}
__device__ inline float bf_lo(unsigned int u) { return __uint_as_float(u << 16); }
__device__ inline float bf_hi(unsigned int u) { return __uint_as_float(u & 0xffff0000u); }

// ---------------------------------------------------------------------------
// fused_gemm_bin: block-role split.
//   blocks [0, gemmBlocks)          : h = x @ W (pure bf16 MFMA, grid-stride)
//   blocks [gemmBlocks, +ntile_e)   : bin_scatter tile of TILE edges
// The two roles are data-independent; co-residency overlaps MFMA/VALU work
// with LDS-sort/atomic work. Shared 32 KB LDS union.
// binCursor is RELATIVE (memset 0 before launch); global address =
// (bin << CAP_SHIFT) + rel, overflow-guarded by rel < BIN_CAP.
// ---------------------------------------------------------------------------
__global__ __launch_bounds__(256) void fused_gemm_bin(const float* __restrict__ x,
                                                      const float* __restrict__ W,
                                                      unsigned short* __restrict__ h,
                                                      const int* __restrict__ src,
                                                      const int* __restrict__ dst,
                                                      int* __restrict__ binCursor,
                                                      unsigned int* __restrict__ binned,
                                                      int n_nodes, int ntiles,
                                                      int n_edges, int nb,
                                                      int gemmBlocks) {
    __shared__ __align__(16) char smem[32768];
    const int tid = threadIdx.x;

    if ((int)blockIdx.x < gemmBlocks) {
        // ------------------- GEMM role -------------------
        unsigned short* Wt = (unsigned short*)smem;  // [128][128] bf16, k-swizzled

        const float4* W4 = (const float4*)W;
#pragma unroll
        for (int i = 0; i < 16; ++i) {
            const int vid = i * 256 + tid;
            const int k = vid >> 5;
            const int c4 = (vid & 31) * 4;
            const float4 w = W4[vid];
            const float* wf = (const float*)&w;
#pragma unroll
            for (int j = 0; j < 4; ++j) {
                const int col = c4 + j;
                const int ksw = k ^ ((col & 7) << 3);
                Wt[col * NDIM + ksw] = f2bf_rne(wf[j]);
            }
        }
        __syncthreads();

        const int wave = tid >> 6;
        const int lane = tid & 63;
        const int lc = lane & 15;
        const int kq = (lane >> 4) * 8;

        for (int tile = blockIdx.x; tile < ntiles; tile += gemmBlocks) {
            const int row0 = tile * 64 + wave * 16;

            int arow = row0 + lc;
            arow = (arow < n_nodes) ? arow : (n_nodes - 1);
            const float* xr = x + (size_t)arow * NDIM;

            f32x4 acc[8];
#pragma unroll
            for (int t = 0; t < 8; ++t) acc[t] = (f32x4){0.f, 0.f, 0.f, 0.f};

#pragma unroll
            for (int ks = 0; ks < 4; ++ks) {
                const int kbase = ks * 32 + kq;
                const float4 v0 = *(const float4*)(xr + kbase);
                const float4 v1 = *(const float4*)(xr + kbase + 4);
                const float* vf0 = (const float*)&v0;
                const float* vf1 = (const float*)&v1;

                short8 ah;
#pragma unroll
                for (int j = 0; j < 4; ++j) {
                    ah[j]     = (short)f2bf_rne(vf0[j]);
                    ah[j + 4] = (short)f2bf_rne(vf1[j]);
                }

#pragma unroll
                for (int t = 0; t < 8; ++t) {
                    const int col = t * 16 + lc;
                    const int ksw = kbase ^ ((col & 7) << 3);
                    const short8 bh = *(const short8*)&Wt[col * NDIM + ksw];
                    acc[t] = __builtin_amdgcn_mfma_f32_16x16x32_bf16(ah, bh, acc[t], 0, 0, 0);
                }
            }

            const int orow0 = row0 + (lane >> 4) * 4;
#pragma unroll
            for (int t = 0; t < 8; ++t) {
#pragma unroll
                for (int r = 0; r < 4; ++r) {
                    const int row = orow0 + r;
                    if (row < n_nodes) {
                        h[(size_t)row * NDIM + t * 16 + lc] = f2bf_rne(acc[t][r]);
                    }
                }
            }
        }
        return;
    }

    // ------------------- BIN role -------------------
    int* lhist  = (int*)smem;                                // 2048 B
    int* lstart = lhist + MAX_BINS;                          // 2048 B
    int* lcur   = lstart + MAX_BINS;                         // 2048 B
    int* lsums  = lcur + MAX_BINS;                           // 1024 B
    unsigned int* lsorted = (unsigned int*)(lsums + 256);    // 16384 B
    unsigned short* lbin  = (unsigned short*)(lsorted + TILE); // 8192 B  (sum 31744)

    const int bblk = (int)blockIdx.x - gemmBlocks;
    const int base = bblk * TILE;
    const int count = min(TILE, n_edges - base);

    for (int i = tid; i < MAX_BINS; i += 256) lhist[i] = 0;
    __syncthreads();

    int mybin[16];
    unsigned int mypacked[16];
#pragma unroll
    for (int j = 0; j < 16; ++j) {
        const int idx = tid + j * 256;  // coalesced
        if (idx < count) {
            const int d = __builtin_nontemporal_load(dst + base + idx);
            const int s = __builtin_nontemporal_load(src + base + idx);
            mybin[j] = d >> BIN_SHIFT;
            mypacked[j] = ((unsigned int)(d & (BIN_NODES - 1)) << 24) | (unsigned int)s;
            atomicAdd(&lhist[mybin[j]], 1);
        } else {
            mybin[j] = -1;
            mypacked[j] = 0;
        }
    }
    __syncthreads();

    // exclusive scan over MAX_BINS (2 elems/thread)
    const int a = lhist[2 * tid], b = lhist[2 * tid + 1];
    lsums[tid] = a + b;
    __syncthreads();
    for (int off = 1; off < 256; off <<= 1) {
        const int tmp = (tid >= off) ? lsums[tid - off] : 0;
        __syncthreads();
        lsums[tid] += tmp;
        __syncthreads();
    }
    const int ex = (tid > 0) ? lsums[tid - 1] : 0;
    lstart[2 * tid] = ex;
    lstart[2 * tid + 1] = ex + a;
    lcur[2 * tid] = ex;
    lcur[2 * tid + 1] = ex + a;
    __syncthreads();

    // LDS scatter into bin-sorted order + bin LUT
#pragma unroll
    for (int j = 0; j < 16; ++j) {
        if (mybin[j] >= 0) {
            const int pos = atomicAdd(&lcur[mybin[j]], 1);
            lsorted[pos] = mypacked[j];
            lbin[pos] = (unsigned short)mybin[j];
        }
    }
    __syncthreads();

    // reserve global runs per bin (lcur becomes RELATIVE base per bin)
    for (int i = tid; i < nb; i += 256) {
        const int c = lhist[i];
        lcur[i] = c ? atomicAdd(&binCursor[i], c) : 0;
    }
    __syncthreads();

    // sequential write-out; per-slot bin via LUT
    for (int p = tid; p < count; p += 256) {
        const int bn = lbin[p];
        const int rel = lcur[bn] + (p - lstart[bn]);
        if (rel < BIN_CAP) {  // overflow guard
            binned[((size_t)bn << CAP_SHIFT) + rel] = lsorted[p];
        }
    }
}

// ---------------------------------------------------------------------------
// csr_fill: one block per bin -> deg[], offs[], srcsorted[] (padded layout).
// ---------------------------------------------------------------------------
__global__ __launch_bounds__(256) void csr_fill(const unsigned int* __restrict__ binned,
                                                const int* __restrict__ binCursor,
                                                int* __restrict__ deg,
                                                int* __restrict__ offs,
                                                int* __restrict__ srcsorted,
                                                int n_nodes) {
    __shared__ int lhist[BIN_NODES];
    __shared__ int lscan[BIN_NODES];
    __shared__ int lcur[BIN_NODES];
    __shared__ unsigned int lin[CSR_CAP];
    __shared__ int lout[CSR_CAP];
    const int b = blockIdx.x;
    const int tid = threadIdx.x;
    const int gbase = b << CAP_SHIFT;
    int count = binCursor[b];           // relative cursor == bin fill count
    count = min(count, BIN_CAP);
    const int node0 = b * BIN_NODES;

    lhist[tid] = 0;
    __syncthreads();

    const bool fits = (count <= CSR_CAP);

    if (fits) {
        for (int p = tid; p < count; p += 256) {
            const unsigned int v = binned[gbase + p];
            lin[p] = v;
            atomicAdd(&lhist[v >> 24], 1);
        }
    } else {
        for (int p = tid; p < count; p += 256) {
            atomicAdd(&lhist[binned[gbase + p] >> 24], 1);
        }
    }
    __syncthreads();

    const int myv = lhist[tid];
    lscan[tid] = myv;
    __syncthreads();
    for (int off = 1; off < 256; off <<= 1) {
        const int tmp = (tid >= off) ? lscan[tid - off] : 0;
        __syncthreads();
        lscan[tid] += tmp;
        __syncthreads();
    }
    const int ex = lscan[tid] - myv;

    const int node = node0 + tid;
    if (node < n_nodes) {
        deg[node] = myv;
        offs[node] = gbase + ex;
    }
    lcur[tid] = ex;
    __syncthreads();

    if (fits) {
        for (int p = tid; p < count; p += 256) {
            const unsigned int v = lin[p];
            const int pos = atomicAdd(&lcur[v >> 24], 1);
            lout[pos] = (int)(v & 0xFFFFFFu);
        }
        __syncthreads();
        for (int p = tid; p < count; p += 256) {
            srcsorted[gbase + p] = lout[p];
        }
    } else {
        for (int p = tid; p < count; p += 256) {
            const unsigned int v = binned[gbase + p];
            const int pos = atomicAdd(&lcur[v >> 24], 1);
            srcsorted[gbase + pos] = (int)(v & 0xFFFFFFu);
        }
    }
}

// ---------------------------------------------------------------------------
// gather_nodes: one wave per node; lane owns 2 cols (1 uint of h).
// 8-deep edge unroll for MLP. out[n] = x[n] + relu(sum h[src] + b)
// ---------------------------------------------------------------------------
__global__ __launch_bounds__(256) void gather_nodes(const unsigned short* __restrict__ h,
                                                    const int* __restrict__ srcsorted,
                                                    const int* __restrict__ offs,
                                                    const int* __restrict__ deg,
                                                    const float* __restrict__ x,
                                                    const float* __restrict__ bias,
                                                    float* __restrict__ out,
                                                    int n_nodes) {
    const int gid = blockIdx.x * 256 + threadIdx.x;
    const int node = gid >> 6;
    if (node >= n_nodes) return;
    const int lane = threadIdx.x & 63;
    const int c = lane * 2;

    const int start = offs[node];
    const int cnt = deg[node];

    float ax = 0.f, ay = 0.f;
    int j = 0;
    for (; j + 8 <= cnt; j += 8) {
        int s[8];
#pragma unroll
        for (int k = 0; k < 8; ++k) s[k] = __builtin_nontemporal_load(srcsorted + start + j + k);
        unsigned int v[8];
#pragma unroll
        for (int k = 0; k < 8; ++k) v[k] = *(const unsigned int*)(h + (size_t)s[k] * NDIM + c);
#pragma unroll
        for (int k = 0; k < 8; ++k) { ax += bf_lo(v[k]); ay += bf_hi(v[k]); }
    }
    for (; j + 4 <= cnt; j += 4) {
        int s[4];
#pragma unroll
        for (int k = 0; k < 4; ++k) s[k] = __builtin_nontemporal_load(srcsorted + start + j + k);
        unsigned int v[4];
#pragma unroll
        for (int k = 0; k < 4; ++k) v[k] = *(const unsigned int*)(h + (size_t)s[k] * NDIM + c);
#pragma unroll
        for (int k = 0; k < 4; ++k) { ax += bf_lo(v[k]); ay += bf_hi(v[k]); }
    }
    for (; j < cnt; ++j) {
        const int s0 = __builtin_nontemporal_load(srcsorted + start + j);
        const unsigned int v0 = *(const unsigned int*)(h + (size_t)s0 * NDIM + c);
        ax += bf_lo(v0);
        ay += bf_hi(v0);
    }

    const float2 xv = *(const float2*)(x + (size_t)node * NDIM + c);
    const float2 bv = *(const float2*)(bias + c);
    float2 r;
    r.x = xv.x + fmaxf(ax + bv.x, 0.f);
    r.y = xv.y + fmaxf(ay + bv.y, 0.f);
    *(float2*)(out + (size_t)node * NDIM + c) = r;
}

// ---------------------------------------------------------------------------
// Fallback GEMM (standalone) + atomic scatter, used only if ws too small.
// ---------------------------------------------------------------------------
__global__ __launch_bounds__(256) void gemm128_bf16(const float* __restrict__ x,
                                                    const float* __restrict__ W,
                                                    unsigned short* __restrict__ h,
                                                    int n_nodes, int ntiles) {
    __shared__ __align__(16) unsigned short Wt[NDIM * NDIM];
    const int tid = threadIdx.x;
    const float4* W4 = (const float4*)W;
#pragma unroll
    for (int i = 0; i < 16; ++i) {
        const int vid = i * 256 + tid;
        const int k = vid >> 5;
        const int c4 = (vid & 31) * 4;
        const float4 w = W4[vid];
        const float* wf = (const float*)&w;
#pragma unroll
        for (int j = 0; j < 4; ++j) {
            const int col = c4 + j;
            const int ksw = k ^ ((col & 7) << 3);
            Wt[col * NDIM + ksw] = f2bf_rne(wf[j]);
        }
    }
    __syncthreads();
    const int wave = tid >> 6;
    const int lane = tid & 63;
    const int lc = lane & 15;
    const int kq = (lane >> 4) * 8;
    for (int tile = blockIdx.x; tile < ntiles; tile += gridDim.x) {
        const int row0 = tile * 64 + wave * 16;
        int arow = row0 + lc;
        arow = (arow < n_nodes) ? arow : (n_nodes - 1);
        const float* xr = x + (size_t)arow * NDIM;
        f32x4 acc[8];
#pragma unroll
        for (int t = 0; t < 8; ++t) acc[t] = (f32x4){0.f, 0.f, 0.f, 0.f};
#pragma unroll
        for (int ks = 0; ks < 4; ++ks) {
            const int kbase = ks * 32 + kq;
            const float4 v0 = *(const float4*)(xr + kbase);
            const float4 v1 = *(const float4*)(xr + kbase + 4);
            const float* vf0 = (const float*)&v0;
            const float* vf1 = (const float*)&v1;
            short8 ah;
#pragma unroll
            for (int j = 0; j < 4; ++j) {
                ah[j]     = (short)f2bf_rne(vf0[j]);
                ah[j + 4] = (short)f2bf_rne(vf1[j]);
            }
#pragma unroll
            for (int t = 0; t < 8; ++t) {
                const int col = t * 16 + lc;
                const int ksw = kbase ^ ((col & 7) << 3);
                const short8 bh = *(const short8*)&Wt[col * NDIM + ksw];
                acc[t] = __builtin_amdgcn_mfma_f32_16x16x32_bf16(ah, bh, acc[t], 0, 0, 0);
            }
        }
        const int orow0 = row0 + (lane >> 4) * 4;
#pragma unroll
        for (int t = 0; t < 8; ++t) {
#pragma unroll
            for (int r = 0; r < 4; ++r) {
                const int row = orow0 + r;
                if (row < n_nodes) {
                    h[(size_t)row * NDIM + t * 16 + lc] = f2bf_rne(acc[t][r]);
                }
            }
        }
    }
}

__global__ __launch_bounds__(256) void scatter_add_bf(const unsigned short* __restrict__ h,
                                                      const int* __restrict__ src,
                                                      const int* __restrict__ dst,
                                                      float* __restrict__ agg,
                                                      int n_edges) {
    const int gid = blockIdx.x * 256 + threadIdx.x;
    const int e = gid >> 6;
    if (e >= n_edges) return;
    const int c = (gid & 63) * 2;
    const int s = src[e];
    const int d = dst[e];
    const unsigned int v = *(const unsigned int*)(h + (size_t)s * NDIM + c);
    float* ap = agg + (size_t)d * NDIM + c;
    atomicAdd(ap + 0, bf_lo(v));
    atomicAdd(ap + 1, bf_hi(v));
}

__global__ __launch_bounds__(256) void finalize(const float* __restrict__ x,
                                                const float* __restrict__ b,
                                                float* __restrict__ out,
                                                int n_vec4) {
    const int i = blockIdx.x * 256 + threadIdx.x;
    if (i >= n_vec4) return;
    float4 xv = ((const float4*)x)[i];
    float4 av = ((float4*)out)[i];
    const int dcol = (i * 4) & (NDIM - 1);
    float4 bv = *(const float4*)(b + dcol);
    float4 r;
    r.x = xv.x + fmaxf(av.x + bv.x, 0.f);
    r.y = xv.y + fmaxf(av.y + bv.y, 0.f);
    r.z = xv.z + fmaxf(av.z + bv.z, 0.f);
    r.w = xv.w + fmaxf(av.w + bv.w, 0.f);
    ((float4*)out)[i] = r;
}

extern "C" void kernel_launch(void* const* d_in, const int* in_sizes, int n_in,
                              void* d_out, int out_size, void* d_ws, size_t ws_size,
                              hipStream_t stream) {
    const float* x    = (const float*)d_in[0];
    const int*   esrc = (const int*)d_in[1];
    const int*   edst = (const int*)d_in[2];
    const float* W    = (const float*)d_in[3];
    const float* b    = (const float*)d_in[4];
    float* out = (float*)d_out;

    const int n_nodes = in_sizes[0] / NDIM;
    const int n_edges = in_sizes[1];
    const int nb = (n_nodes + BIN_NODES - 1) / BIN_NODES;
    const int ntiles = (n_nodes + 63) / 64;

    // Workspace layout
    unsigned short* h = (unsigned short*)d_ws;                 // N*128 bf16
    int* deg       = (int*)(h + (size_t)n_nodes * NDIM);       // N
    int* offs      = deg + n_nodes;                            // N
    int* binCursor = offs + n_nodes;                           // MAX_BINS
    unsigned int* binned = (unsigned int*)(binCursor + MAX_BINS);  // nb*BIN_CAP
    int* srcsorted = (int*)(binned + ((size_t)nb << CAP_SHIFT));   // nb*BIN_CAP

    const size_t required = (size_t)n_nodes * NDIM * 2 +
                            (size_t)(2 * n_nodes + MAX_BINS) * 4 +
                            ((size_t)nb << CAP_SHIFT) * 8;

    if (nb <= MAX_BINS && ws_size >= required) {
        hipMemsetAsync(binCursor, 0, (size_t)nb * sizeof(int), stream);

        const int gemmBlocks = (ntiles < 1024) ? ntiles : 1024;
        const int ntile_e = (n_edges + TILE - 1) / TILE;
        fused_gemm_bin<<<gemmBlocks + ntile_e, 256, 0, stream>>>(
            x, W, h, esrc, edst, binCursor, binned,
            n_nodes, ntiles, n_edges, nb, gemmBlocks);

        csr_fill<<<nb, 256, 0, stream>>>(binned, binCursor, deg, offs, srcsorted, n_nodes);

        const long long gthreads = (long long)n_nodes * 64;
        gather_nodes<<<(int)((gthreads + 255) / 256), 256, 0, stream>>>(
            h, srcsorted, offs, deg, x, b, out, n_nodes);
    } else {
        // fallback: standalone gemm + atomic scatter
        const int gblocks = (ntiles < 2048) ? ntiles : 2048;
        gemm128_bf16<<<gblocks, 256, 0, stream>>>(x, W, h, n_nodes, ntiles);
        hipMemsetAsync(d_out, 0, (size_t)out_size * sizeof(float), stream);
        const long long st = (long long)n_edges * 64;
        scatter_add_bf<<<(int)((st + 255) / 256), 256, 0, stream>>>(h, esrc, edst, out, n_edges);
        const int n_vec4 = n_nodes * NDIM / 4;
        finalize<<<(n_vec4 + 255) / 256, 256, 0, stream>>>(x, b, out, n_vec4);
    }
}

// Round 12
// 136.317 us; speedup vs baseline: 8.2243x; 1.0336x over previous
//
#include <hip/hip_runtime.h>

#define NDIM 128
#define BIN_SHIFT 7
#define BIN_NODES 128          // 1 << BIN_SHIFT
#define MAX_BINS 1024          // supports up to 131072 nodes
#define TILE 4096              // edges per bin-role block
#define CAP_SHIFT 12
#define BIN_CAP 4096           // padded per-bin capacity (avg fill ~2046, +45 sigma)
#define LOUT_CAP 6144          // per-bin LDS sorted-src capacity in gather_bin

typedef __attribute__((ext_vector_type(8))) short short8;
typedef __attribute__((ext_vector_type(4))) float f32x4;

__device__ inline unsigned short f2bf_rne(float f) {
    unsigned int u = __float_as_uint(f);
    unsigned int r = u + 0x7fffu + ((u >> 16) & 1u);
    return (unsigned short)(r >> 16);
}
__device__ inline float bf2f(unsigned short s) {
    return __uint_as_float(((unsigned int)s) << 16);
}
__device__ inline float bf_lo(unsigned int u) { return __uint_as_float(u << 16); }
__device__ inline float bf_hi(unsigned int u) { return __uint_as_float(u & 0xffff0000u); }

// ---------------------------------------------------------------------------
// fused_gemm_bin: block-role split (data-independent roles co-resident).
//   blocks [0, gemmBlocks)        : h = x @ W (pure bf16 MFMA, grid-stride)
//   blocks [gemmBlocks, +ntile_e) : bin-scatter tile of TILE edges into
//                                   128-node bins (packed dstLow<<24|src).
// binCursor is RELATIVE (memset 0 before launch).
// ---------------------------------------------------------------------------
__global__ __launch_bounds__(256) void fused_gemm_bin(const float* __restrict__ x,
                                                      const float* __restrict__ W,
                                                      unsigned short* __restrict__ h,
                                                      const int* __restrict__ src,
                                                      const int* __restrict__ dst,
                                                      int* __restrict__ binCursor,
                                                      unsigned int* __restrict__ binned,
                                                      int n_nodes, int ntiles,
                                                      int n_edges, int nb,
                                                      int gemmBlocks) {
    __shared__ __align__(16) char smem[38144];
    const int tid = threadIdx.x;

    if ((int)blockIdx.x < gemmBlocks) {
        // ------------------- GEMM role -------------------
        unsigned short* Wt = (unsigned short*)smem;  // [128][128] bf16, k-swizzled

        const float4* W4 = (const float4*)W;
#pragma unroll
        for (int i = 0; i < 16; ++i) {
            const int vid = i * 256 + tid;
            const int k = vid >> 5;
            const int c4 = (vid & 31) * 4;
            const float4 w = W4[vid];
            const float* wf = (const float*)&w;
#pragma unroll
            for (int j = 0; j < 4; ++j) {
                const int col = c4 + j;
                const int ksw = k ^ ((col & 7) << 3);
                Wt[col * NDIM + ksw] = f2bf_rne(wf[j]);
            }
        }
        __syncthreads();

        const int wave = tid >> 6;
        const int lane = tid & 63;
        const int lc = lane & 15;
        const int kq = (lane >> 4) * 8;

        for (int tile = blockIdx.x; tile < ntiles; tile += gemmBlocks) {
            const int row0 = tile * 64 + wave * 16;

            int arow = row0 + lc;
            arow = (arow < n_nodes) ? arow : (n_nodes - 1);
            const float* xr = x + (size_t)arow * NDIM;

            f32x4 acc[8];
#pragma unroll
            for (int t = 0; t < 8; ++t) acc[t] = (f32x4){0.f, 0.f, 0.f, 0.f};

#pragma unroll
            for (int ks = 0; ks < 4; ++ks) {
                const int kbase = ks * 32 + kq;
                const float4 v0 = *(const float4*)(xr + kbase);
                const float4 v1 = *(const float4*)(xr + kbase + 4);
                const float* vf0 = (const float*)&v0;
                const float* vf1 = (const float*)&v1;

                short8 ah;
#pragma unroll
                for (int j = 0; j < 4; ++j) {
                    ah[j]     = (short)f2bf_rne(vf0[j]);
                    ah[j + 4] = (short)f2bf_rne(vf1[j]);
                }

#pragma unroll
                for (int t = 0; t < 8; ++t) {
                    const int col = t * 16 + lc;
                    const int ksw = kbase ^ ((col & 7) << 3);
                    const short8 bh = *(const short8*)&Wt[col * NDIM + ksw];
                    acc[t] = __builtin_amdgcn_mfma_f32_16x16x32_bf16(ah, bh, acc[t], 0, 0, 0);
                }
            }

            const int orow0 = row0 + (lane >> 4) * 4;
#pragma unroll
            for (int t = 0; t < 8; ++t) {
#pragma unroll
                for (int r = 0; r < 4; ++r) {
                    const int row = orow0 + r;
                    if (row < n_nodes) {
                        h[(size_t)row * NDIM + t * 16 + lc] = f2bf_rne(acc[t][r]);
                    }
                }
            }
        }
        return;
    }

    // ------------------- BIN role -------------------
    int* lhist  = (int*)smem;                                  //  4096 B
    int* lstart = lhist + MAX_BINS;                            //  4096 B
    int* lcur   = lstart + MAX_BINS;                           //  4096 B
    int* lsums  = lcur + MAX_BINS;                             //  1024 B
    unsigned int* lsorted = (unsigned int*)(lsums + 256);      // 16384 B
    unsigned short* lbin  = (unsigned short*)(lsorted + TILE); //  8192 B (sum 37888)

    const int bblk = (int)blockIdx.x - gemmBlocks;
    const int base = bblk * TILE;
    const int count = min(TILE, n_edges - base);

    for (int i = tid; i < MAX_BINS; i += 256) lhist[i] = 0;
    __syncthreads();

    int mybin[16];
    unsigned int mypacked[16];
#pragma unroll
    for (int j = 0; j < 16; ++j) {
        const int idx = tid + j * 256;  // coalesced
        if (idx < count) {
            const int d = __builtin_nontemporal_load(dst + base + idx);
            const int s = __builtin_nontemporal_load(src + base + idx);
            mybin[j] = d >> BIN_SHIFT;
            mypacked[j] = ((unsigned int)(d & (BIN_NODES - 1)) << 24) | (unsigned int)s;
            atomicAdd(&lhist[mybin[j]], 1);
        } else {
            mybin[j] = -1;
            mypacked[j] = 0;
        }
    }
    __syncthreads();

    // exclusive scan over MAX_BINS=1024 (4 elems/thread)
    const int a0 = lhist[4 * tid], a1 = lhist[4 * tid + 1];
    const int a2 = lhist[4 * tid + 2], a3 = lhist[4 * tid + 3];
    lsums[tid] = a0 + a1 + a2 + a3;
    __syncthreads();
    for (int off = 1; off < 256; off <<= 1) {
        const int tmp = (tid >= off) ? lsums[tid - off] : 0;
        __syncthreads();
        lsums[tid] += tmp;
        __syncthreads();
    }
    int ex = (tid > 0) ? lsums[tid - 1] : 0;
    lstart[4 * tid] = ex;
    lcur[4 * tid] = ex;
    ex += a0;
    lstart[4 * tid + 1] = ex;
    lcur[4 * tid + 1] = ex;
    ex += a1;
    lstart[4 * tid + 2] = ex;
    lcur[4 * tid + 2] = ex;
    ex += a2;
    lstart[4 * tid + 3] = ex;
    lcur[4 * tid + 3] = ex;
    __syncthreads();

    // LDS scatter into bin-sorted order + bin LUT
#pragma unroll
    for (int j = 0; j < 16; ++j) {
        if (mybin[j] >= 0) {
            const int pos = atomicAdd(&lcur[mybin[j]], 1);
            lsorted[pos] = mypacked[j];
            lbin[pos] = (unsigned short)mybin[j];
        }
    }
    __syncthreads();

    // reserve global runs per bin (lcur becomes RELATIVE base per bin)
    for (int i = tid; i < nb; i += 256) {
        const int c = lhist[i];
        lcur[i] = c ? atomicAdd(&binCursor[i], c) : 0;
    }
    __syncthreads();

    // sequential write-out; per-slot bin via LUT
    for (int p = tid; p < count; p += 256) {
        const int bn = lbin[p];
        const int rel = lcur[bn] + (p - lstart[bn]);
        if (rel < BIN_CAP) {  // overflow guard
            binned[((size_t)bn << CAP_SHIFT) + rel] = lsorted[p];
        }
    }
}

// ---------------------------------------------------------------------------
// gather_bin: one block (256 thr) per 128-node bin. In-LDS CSR build
// (hist -> scan -> scatter of src indices into lout grouped per node), then
// 4 waves gather 32 nodes each: 8-deep h-row unroll, fused epilogue
// out[n] = x[n] + relu(sum h[src] + b). src list reads are LDS broadcasts.
// ---------------------------------------------------------------------------
__global__ __launch_bounds__(256) void gather_bin(const unsigned short* __restrict__ h,
                                                  const unsigned int* __restrict__ binned,
                                                  const int* __restrict__ binCursor,
                                                  const float* __restrict__ x,
                                                  const float* __restrict__ bias,
                                                  float* __restrict__ out,
                                                  int n_nodes) {
    __shared__ int lhist[BIN_NODES];
    __shared__ int lstart[BIN_NODES];
    __shared__ int lcur[BIN_NODES];
    __shared__ int lout[LOUT_CAP];
    const int b = blockIdx.x;
    const int tid = threadIdx.x;
    const size_t gbase = (size_t)b << CAP_SHIFT;
    int count = min(binCursor[b], BIN_CAP);
    const int node0 = b * BIN_NODES;

    if (tid < BIN_NODES) lhist[tid] = 0;
    __syncthreads();

    // pass 1: histogram per node
    for (int p = tid; p < count; p += 256) {
        atomicAdd(&lhist[binned[gbase + p] >> 24], 1);
    }
    __syncthreads();

    // inclusive scan of lhist[128] in lstart (Hillis-Steele, 128 lanes active)
    if (tid < BIN_NODES) lstart[tid] = lhist[tid];
    __syncthreads();
    for (int off = 1; off < BIN_NODES; off <<= 1) {
        int v = 0;
        if (tid < BIN_NODES && tid >= off) v = lstart[tid - off];
        __syncthreads();
        if (tid < BIN_NODES && tid >= off) lstart[tid] += v;
        __syncthreads();
    }
    int ex = 0;
    if (tid < BIN_NODES) ex = (tid > 0) ? lstart[tid - 1] : 0;
    __syncthreads();
    if (tid < BIN_NODES) {
        lstart[tid] = ex;
        lcur[tid] = ex;
    }
    __syncthreads();

    // pass 2: scatter src into per-node groups (binned is L2-hot)
    for (int p = tid; p < count; p += 256) {
        const unsigned int v = binned[gbase + p];
        const int pos = atomicAdd(&lcur[v >> 24], 1);
        if (pos < LOUT_CAP) lout[pos] = (int)(v & 0xFFFFFFu);
    }
    __syncthreads();

    // gather: wave w handles local nodes w*32 .. w*32+31 serially
    const int wave = tid >> 6;
    const int lane = tid & 63;
    const int c = lane * 2;
    const float2 bv = *(const float2*)(bias + c);

#pragma unroll 1
    for (int i = 0; i < 32; ++i) {
        const int ln = wave * 32 + i;
        const int node = node0 + ln;
        if (node >= n_nodes) break;
        const int start = lstart[ln];
        int cnt = lhist[ln];
        if (start + cnt > LOUT_CAP) cnt = LOUT_CAP - start;  // never in practice

        float ax = 0.f, ay = 0.f;
        int j = 0;
        for (; j + 8 <= cnt; j += 8) {
            int s[8];
#pragma unroll
            for (int k = 0; k < 8; ++k) s[k] = lout[start + j + k];
            unsigned int v[8];
#pragma unroll
            for (int k = 0; k < 8; ++k) v[k] = *(const unsigned int*)(h + (size_t)s[k] * NDIM + c);
#pragma unroll
            for (int k = 0; k < 8; ++k) { ax += bf_lo(v[k]); ay += bf_hi(v[k]); }
        }
        for (; j + 4 <= cnt; j += 4) {
            int s[4];
#pragma unroll
            for (int k = 0; k < 4; ++k) s[k] = lout[start + j + k];
            unsigned int v[4];
#pragma unroll
            for (int k = 0; k < 4; ++k) v[k] = *(const unsigned int*)(h + (size_t)s[k] * NDIM + c);
#pragma unroll
            for (int k = 0; k < 4; ++k) { ax += bf_lo(v[k]); ay += bf_hi(v[k]); }
        }
        for (; j < cnt; ++j) {
            const int s0 = lout[start + j];
            const unsigned int v0 = *(const unsigned int*)(h + (size_t)s0 * NDIM + c);
            ax += bf_lo(v0);
            ay += bf_hi(v0);
        }

        const float2 xv = *(const float2*)(x + (size_t)node * NDIM + c);
        float2 r;
        r.x = xv.x + fmaxf(ax + bv.x, 0.f);
        r.y = xv.y + fmaxf(ay + bv.y, 0.f);
        *(float2*)(out + (size_t)node * NDIM + c) = r;
    }
}

// ---------------------------------------------------------------------------
// Fallback GEMM (standalone) + atomic scatter, used only if ws too small.
// ---------------------------------------------------------------------------
__global__ __launch_bounds__(256) void gemm128_bf16(const float* __restrict__ x,
                                                    const float* __restrict__ W,
                                                    unsigned short* __restrict__ h,
                                                    int n_nodes, int ntiles) {
    __shared__ __align__(16) unsigned short Wt[NDIM * NDIM];
    const int tid = threadIdx.x;
    const float4* W4 = (const float4*)W;
#pragma unroll
    for (int i = 0; i < 16; ++i) {
        const int vid = i * 256 + tid;
        const int k = vid >> 5;
        const int c4 = (vid & 31) * 4;
        const float4 w = W4[vid];
        const float* wf = (const float*)&w;
#pragma unroll
        for (int j = 0; j < 4; ++j) {
            const int col = c4 + j;
            const int ksw = k ^ ((col & 7) << 3);
            Wt[col * NDIM + ksw] = f2bf_rne(wf[j]);
        }
    }
    __syncthreads();
    const int wave = tid >> 6;
    const int lane = tid & 63;
    const int lc = lane & 15;
    const int kq = (lane >> 4) * 8;
    for (int tile = blockIdx.x; tile < ntiles; tile += gridDim.x) {
        const int row0 = tile * 64 + wave * 16;
        int arow = row0 + lc;
        arow = (arow < n_nodes) ? arow : (n_nodes - 1);
        const float* xr = x + (size_t)arow * NDIM;
        f32x4 acc[8];
#pragma unroll
        for (int t = 0; t < 8; ++t) acc[t] = (f32x4){0.f, 0.f, 0.f, 0.f};
#pragma unroll
        for (int ks = 0; ks < 4; ++ks) {
            const int kbase = ks * 32 + kq;
            const float4 v0 = *(const float4*)(xr + kbase);
            const float4 v1 = *(const float4*)(xr + kbase + 4);
            const float* vf0 = (const float*)&v0;
            const float* vf1 = (const float*)&v1;
            short8 ah;
#pragma unroll
            for (int j = 0; j < 4; ++j) {
                ah[j]     = (short)f2bf_rne(vf0[j]);
                ah[j + 4] = (short)f2bf_rne(vf1[j]);
            }
#pragma unroll
            for (int t = 0; t < 8; ++t) {
                const int col = t * 16 + lc;
                const int ksw = kbase ^ ((col & 7) << 3);
                const short8 bh = *(const short8*)&Wt[col * NDIM + ksw];
                acc[t] = __builtin_amdgcn_mfma_f32_16x16x32_bf16(ah, bh, acc[t], 0, 0, 0);
            }
        }
        const int orow0 = row0 + (lane >> 4) * 4;
#pragma unroll
        for (int t = 0; t < 8; ++t) {
#pragma unroll
            for (int r = 0; r < 4; ++r) {
                const int row = orow0 + r;
                if (row < n_nodes) {
                    h[(size_t)row * NDIM + t * 16 + lc] = f2bf_rne(acc[t][r]);
                }
            }
        }
    }
}

__global__ __launch_bounds__(256) void scatter_add_bf(const unsigned short* __restrict__ h,
                                                      const int* __restrict__ src,
                                                      const int* __restrict__ dst,
                                                      float* __restrict__ agg,
                                                      int n_edges) {
    const int gid = blockIdx.x * 256 + threadIdx.x;
    const int e = gid >> 6;
    if (e >= n_edges) return;
    const int c = (gid & 63) * 2;
    const int s = src[e];
    const int d = dst[e];
    const unsigned int v = *(const unsigned int*)(h + (size_t)s * NDIM + c);
    float* ap = agg + (size_t)d * NDIM + c;
    atomicAdd(ap + 0, bf_lo(v));
    atomicAdd(ap + 1, bf_hi(v));
}

__global__ __launch_bounds__(256) void finalize(const float* __restrict__ x,
                                                const float* __restrict__ b,
                                                float* __restrict__ out,
                                                int n_vec4) {
    const int i = blockIdx.x * 256 + threadIdx.x;
    if (i >= n_vec4) return;
    float4 xv = ((const float4*)x)[i];
    float4 av = ((float4*)out)[i];
    const int dcol = (i * 4) & (NDIM - 1);
    float4 bv = *(const float4*)(b + dcol);
    float4 r;
    r.x = xv.x + fmaxf(av.x + bv.x, 0.f);
    r.y = xv.y + fmaxf(av.y + bv.y, 0.f);
    r.z = xv.z + fmaxf(av.z + bv.z, 0.f);
    r.w = xv.w + fmaxf(av.w + bv.w, 0.f);
    ((float4*)out)[i] = r;
}

extern "C" void kernel_launch(void* const* d_in, const int* in_sizes, int n_in,
                              void* d_out, int out_size, void* d_ws, size_t ws_size,
                              hipStream_t stream) {
    const float* x    = (const float*)d_in[0];
    const int*   esrc = (const int*)d_in[1];
    const int*   edst = (const int*)d_in[2];
    const float* W    = (const float*)d_in[3];
    const float* b    = (const float*)d_in[4];
    float* out = (float*)d_out;

    const int n_nodes = in_sizes[0] / NDIM;
    const int n_edges = in_sizes[1];
    const int nb = (n_nodes + BIN_NODES - 1) / BIN_NODES;
    const int ntiles = (n_nodes + 63) / 64;

    // Workspace layout
    unsigned short* h = (unsigned short*)d_ws;                 // N*128 bf16
    int* binCursor = (int*)(h + (size_t)n_nodes * NDIM);       // MAX_BINS
    unsigned int* binned = (unsigned int*)(binCursor + MAX_BINS);  // nb*BIN_CAP

    const size_t required = (size_t)n_nodes * NDIM * 2 +
                            (size_t)MAX_BINS * 4 +
                            ((size_t)nb << CAP_SHIFT) * 4;

    if (nb <= MAX_BINS && ws_size >= required) {
        hipMemsetAsync(binCursor, 0, (size_t)nb * sizeof(int), stream);

        const int gemmBlocks = (ntiles < 1024) ? ntiles : 1024;
        const int ntile_e = (n_edges + TILE - 1) / TILE;
        fused_gemm_bin<<<gemmBlocks + ntile_e, 256, 0, stream>>>(
            x, W, h, esrc, edst, binCursor, binned,
            n_nodes, ntiles, n_edges, nb, gemmBlocks);

        gather_bin<<<nb, 256, 0, stream>>>(h, binned, binCursor, x, b, out, n_nodes);
    } else {
        // fallback: standalone gemm + atomic scatter
        const int gblocks = (ntiles < 2048) ? ntiles : 2048;
        gemm128_bf16<<<gblocks, 256, 0, stream>>>(x, W, h, n_nodes, ntiles);
        hipMemsetAsync(d_out, 0, (size_t)out_size * sizeof(float), stream);
        const long long st = (long long)n_edges * 64;
        scatter_add_bf<<<(int)((st + 255) / 256), 256, 0, stream>>>(h, esrc, edst, out, n_edges);
        const int n_vec4 = n_nodes * NDIM / 4;
        finalize<<<(n_vec4 + 255) / 256, 256, 0, stream>>>(x, b, out, n_vec4);
    }
}